// Round 6
// baseline (1603.344 us; speedup 1.0000x reference)
//
#include <hip/hip_runtime.h>
#include <hip/hip_bf16.h>

// NestedFeedForward, Round 5: single persistent mega-kernel (1024 blocks =
// exactly 4/CU) with manual device-scope grid barriers. Kills ~75-100us of
// inter-launch dead time measured in R4 (sum-of-parts <=290us vs 364 wall).
// Phases: hist+weight-cvt (overlapped) | scan/meta | scatter | x-cvt |
// gemm1 (4 balanced tiles/block) | gemm2 (128x128, compute-first map).

typedef __bf16 bf16x8 __attribute__((ext_vector_type(8)));
typedef float f32x4 __attribute__((ext_vector_type(4)));

#define M_TOK   16384
#define DIM     1024
#define HID     4096
#define NBLK    1024

// meta (ints at ws+0):
#define META_T     31
#define META_BAR   32     // 8 barrier slots (pre-zeroed each launch)
#define META_HIST  64     // 64 blocks x 4 experts
#define META_BASE2 384    // 64 x 4 scatter bases
#define META_BLK   640    // 128 kmax per 128-row block
#define META_MAP   768    // 1024 gemm2 tiles, compute-first
#define META_RT    2048   // 16384 rowtok

__device__ inline unsigned short f2bf(float f) {
  unsigned int u = __float_as_uint(f);
  u += 0x7fffu + ((u >> 16) & 1u);      // RNE; inputs finite
  return (unsigned short)(u >> 16);
}

// gelu with A&S 7.1.26 erf: abs err <= ~2.5e-5 (system absmax 0.0039 vs 0.0216)
__device__ inline float gelu_f(float v) {
  float z = fabsf(v) * 0.7071067811865475f;
  float t = __builtin_amdgcn_rcpf(fmaf(0.3275911f, z, 1.0f));
  float p = fmaf(t, 1.061405429f, -1.453152027f);
  p = fmaf(t, p, 1.421413741f);
  p = fmaf(t, p, -0.284496736f);
  p = fmaf(t, p, 0.254829592f);
  p = p * t;
  float E = __expf(-0.5f * v * v);
  float er = fmaf(-p, E, 1.0f);
  er = copysignf(er, v);
  return 0.5f * v * (1.0f + er);
}

__device__ inline void async_copy16(const void* g, void* s) {
  __builtin_amdgcn_global_load_lds(
      (const __attribute__((address_space(1))) unsigned int*)g,
      (__attribute__((address_space(3))) unsigned int*)s,
      16, 0, 0);
}

// Stage a 128-row x 64-col bf16 tile into 16 KB LDS with XOR chunk swizzle
// (2-way aliasing on the b128 readbacks = free, m136).
template<int LDK>
__device__ inline void stage_tile(const unsigned short* __restrict__ g,
                                  int row0, int k0, char* lds) {
  const char* gbase = (const char*)g;
  int tid = threadIdx.x;
#pragma unroll
  for (int i = 0; i < 4; ++i) {
    int q = i * 256 + tid;          // 1024 chunks of 16B
    int r = q >> 3;                 // tile row 0..127
    int c = q & 7;                  // LDS chunk within row
    int gc = c ^ (r & 7);           // swizzled source chunk
    const void* gp = gbase + ((size_t)(row0 + r) * LDK + (size_t)k0 + gc * 8) * 2;
    async_copy16(gp, lds + (size_t)q * 16);
  }
}

// Manual grid barrier. Protocol: EVERY thread fences (drains its own stores
// to the device-coherent point: vmcnt + L2 writeback), block syncs, tid0 does
// release-add then acquire-spin, fence (L1 inv), block syncs. All cross-block
// data here is write-once -> barrier -> read, so no stale-line hazards remain.
__device__ inline void grid_barrier(int* bar) {
  __threadfence();
  __syncthreads();
  if (threadIdx.x == 0) {
    __hip_atomic_fetch_add(bar, 1, __ATOMIC_RELEASE, __HIP_MEMORY_SCOPE_AGENT);
    while (__hip_atomic_load(bar, __ATOMIC_ACQUIRE, __HIP_MEMORY_SCOPE_AGENT) < NBLK)
      __builtin_amdgcn_s_sleep(2);
    __threadfence();
  }
  __syncthreads();
}

__global__ void zero_bar_kernel(int* meta) {
  if (threadIdx.x < 8) meta[META_BAR + threadIdx.x] = 0;
}

__global__ __launch_bounds__(256, 4) void mega_kernel(
    const float* __restrict__ x,  const float* __restrict__ w1,
    const float* __restrict__ b1, const float* __restrict__ w2,
    const float* __restrict__ b2, const int* __restrict__ tm,
    int* __restrict__ meta,
    unsigned short* __restrict__ xb,  unsigned short* __restrict__ w1b,
    unsigned short* __restrict__ w2b, unsigned short* __restrict__ hb,
    float* __restrict__ out)
{
  __shared__ char smem[32768];
  const int blk = blockIdx.x;
  const int tid = threadIdx.x;
  int* bar = meta + META_BAR;

  // ---------- Phase A: histogram (blk<64) | weight convert (blk>=64) ----------
  if (blk < 64) {
    int* h4 = (int*)smem;
    if (tid < 4) h4[tid] = 0;
    __syncthreads();
    atomicAdd(&h4[tm[blk * 256 + tid]], 1);
    __syncthreads();
    if (tid < 4) meta[META_HIST + blk * 4 + tid] = h4[tid];
  } else {
    for (int c = blk - 64; c < 8192; c += 960) {   // 8192 chunks of 1024 floats
      const float* src = (c < 4096) ? w1 : w2;
      unsigned short* dst = (c < 4096) ? w1b : w2b;
      size_t i = (size_t)(c & 4095) * 1024 + tid * 4;
      float4 v = *(const float4*)(src + i);
      ushort4 o;
      o.x = f2bf(v.x); o.y = f2bf(v.y); o.z = f2bf(v.z); o.w = f2bf(v.w);
      *(ushort4*)(dst + i) = o;
    }
  }
  grid_barrier(bar + 0);

  // ---------- Phase B: scan + metadata (block 0 only) ----------
  if (blk == 0) {
    int* sb  = (int*)smem;            // [5]
    int* cbl = (int*)smem + 8;        // [128]
    int* pfx = (int*)smem + 160;      // [129]
    if (tid == 0) {
      int t0 = 0, t1 = 0, t2 = 0, t3 = 0;
      for (int b = 0; b < 64; ++b) {
        t0 += meta[META_HIST + b * 4 + 0];
        t1 += meta[META_HIST + b * 4 + 1];
        t2 += meta[META_HIST + b * 4 + 2];
        t3 += meta[META_HIST + b * 4 + 3];
      }
      sb[0] = 0; sb[1] = t0; sb[2] = t0 + t1; sb[3] = t0 + t1 + t2; sb[4] = M_TOK;
      int r0 = sb[0], r1 = sb[1], r2 = sb[2], r3 = sb[3];
      for (int b = 0; b < 64; ++b) {
        meta[META_BASE2 + b * 4 + 0] = r0; r0 += meta[META_HIST + b * 4 + 0];
        meta[META_BASE2 + b * 4 + 1] = r1; r1 += meta[META_HIST + b * 4 + 1];
        meta[META_BASE2 + b * 4 + 2] = r2; r2 += meta[META_HIST + b * 4 + 2];
        meta[META_BASE2 + b * 4 + 3] = r3; r3 += meta[META_HIST + b * 4 + 3];
      }
    }
    __syncthreads();
    if (tid < 128) {
      int last = tid * 128 + 127;
      int e = (last >= sb[1]) + (last >= sb[2]) + (last >= sb[3]);
      meta[META_BLK + tid] = 128 << e;           // gemm1 K-trim
      cbl[tid] = 1 << e;                         // gemm2 compute colblocks
    }
    __syncthreads();
    if (tid == 0) {
      int a = 0;
      for (int j = 0; j < 128; ++j) { pfx[j] = a; a += cbl[j]; }
      pfx[128] = a;
      meta[META_T] = a;
    }
    __syncthreads();
    if (tid < 128) {
      int n = cbl[tid], p = pfx[tid];
      for (int c = 0; c < n; ++c) meta[META_MAP + p + c] = tid * 8 + c;
      int zp = pfx[128] + 8 * tid - pfx[tid];
      for (int c = n; c < 8; ++c) meta[META_MAP + zp + (c - n)] = tid * 8 + c;
    }
  }
  grid_barrier(bar + 1);

  // ---------- Phase C: deterministic scatter (blk<64) ----------
  if (blk < 64) {
    int* cnt = (int*)smem;            // [256*5], stride 5 -> conflict-free
    int t = blk * 256 + tid;
    int e = tm[t];
    cnt[tid * 5 + 0] = (e == 0); cnt[tid * 5 + 1] = (e == 1);
    cnt[tid * 5 + 2] = (e == 2); cnt[tid * 5 + 3] = (e == 3);
    __syncthreads();
    for (int s = 1; s < 256; s <<= 1) {          // inclusive scan, 4 lanes
      int v0 = 0, v1 = 0, v2 = 0, v3 = 0;
      if (tid >= s) {
        v0 = cnt[(tid - s) * 5 + 0]; v1 = cnt[(tid - s) * 5 + 1];
        v2 = cnt[(tid - s) * 5 + 2]; v3 = cnt[(tid - s) * 5 + 3];
      }
      __syncthreads();
      cnt[tid * 5 + 0] += v0; cnt[tid * 5 + 1] += v1;
      cnt[tid * 5 + 2] += v2; cnt[tid * 5 + 3] += v3;
      __syncthreads();
    }
    int rank = cnt[tid * 5 + e] - 1;
    int pos = meta[META_BASE2 + blk * 4 + e] + rank;
    meta[META_RT + pos] = t | (e << 14);
  }
  grid_barrier(bar + 2);

  // ---------- Phase D: x gather + bf16 convert (all blocks) ----------
  {
    int d = tid * 4;
    for (int i = 0; i < 16; ++i) {
      int pos = blk * 16 + i;
      int mt = meta[META_RT + pos];
      int t = mt & 0x3FFF;
      int din = 128 << (mt >> 14);
      float4 v = *(const float4*)(x + (size_t)t * DIM + d);
      ushort4 o;
      if (d < din) {                  // din multiple of 128 -> float4-uniform
        o.x = f2bf(v.x); o.y = f2bf(v.y); o.z = f2bf(v.z); o.w = f2bf(v.w);
      } else {
        o.x = 0; o.y = 0; o.z = 0; o.w = 0;
      }
      *(ushort4*)(xb + (size_t)pos * DIM + d) = o;
    }
  }
  grid_barrier(bar + 3);

  // ---------- Phase E: gemm1, 4 tiles/block (one per K-tier: balanced) ----------
  {
    char* As = smem;
    char* Bs = smem + 16384;
    int lane = tid & 63, quad = lane >> 4, l15 = lane & 15;
    int wave = tid >> 6, wm = wave & 1, wn = wave >> 1;
    int chb = (quad ^ (l15 & 7)) << 4;

    for (int it = 0; it < 4; ++it) {
      int tile = it * 1024 + blk;
      int rowblk = 127 - (tile >> 5);            // high-K first
      int row0 = rowblk * 128, col0 = (tile & 31) * 128;
      int kmax = meta[META_BLK + rowblk];

      f32x4 acc[4][4] = {};
      for (int k0 = 0; k0 < kmax; k0 += 64) {
        __syncthreads();
        stage_tile<DIM>(xb, row0, k0, As);
        stage_tile<DIM>(w1b, col0, k0, Bs);
        __syncthreads();
#pragma unroll
        for (int kk = 0; kk < 2; ++kk) {
          int xo = chb ^ (kk << 6);
          bf16x8 af[4], bg[4];
#pragma unroll
          for (int mt = 0; mt < 4; ++mt)
            af[mt] = *(const bf16x8*)(As + (wm * 64 + mt * 16 + l15) * 128 + xo);
#pragma unroll
          for (int nt = 0; nt < 4; ++nt)
            bg[nt] = *(const bf16x8*)(Bs + (wn * 64 + nt * 16 + l15) * 128 + xo);
#pragma unroll
          for (int mt = 0; mt < 4; ++mt)
#pragma unroll
            for (int nt = 0; nt < 4; ++nt)
              acc[mt][nt] = __builtin_amdgcn_mfma_f32_16x16x32_bf16(
                  af[mt], bg[nt], acc[mt][nt], 0, 0, 0);
        }
      }
      // direct-store epilogue (measured faster than LDS round-trip)
      int t_base = row0 + wm * 64;
      int f_base = col0 + wn * 64;
#pragma unroll
      for (int nt = 0; nt < 4; ++nt) {
        int f = f_base + nt * 16 + l15;
        float bv = b1[f];
#pragma unroll
        for (int mt = 0; mt < 4; ++mt) {
#pragma unroll
          for (int r = 0; r < 4; ++r) {
            int t = t_base + mt * 16 + quad * 4 + r;
            float v = gelu_f(acc[mt][nt][r] + bv);
            hb[(size_t)t * HID + f] = f2bf(v);
          }
        }
      }
    }
  }
  grid_barrier(bar + 4);

  // ---------- Phase F: gemm2, 128x128, 1 tile/block ----------
  {
    int T = meta[META_T];
    int b2i = (blk * 997) & 1023;               // shuffle for CU balance
    int mp = meta[META_MAP + b2i];
    int row0 = (mp >> 3) * 128, col0 = (mp & 7) * 128;
    const int* rowtok = meta + META_RT;

    if (b2i >= T) {
      float4 z = make_float4(0.f, 0.f, 0.f, 0.f);
#pragma unroll
      for (int i = 0; i < 16; ++i) {
        int idx = i * 256 + tid;                // 4096 float4 = 128x128 tile
        int r = idx >> 5;
        int col = (idx & 31) * 4;
        int t = rowtok[row0 + r] & 0x3FFF;
        *(float4*)(out + (size_t)t * DIM + col0 + col) = z;
      }
    } else {
      char* As = smem;
      char* Bs = smem + 16384;
      int lane = tid & 63, quad = lane >> 4, l15 = lane & 15;
      int wave = tid >> 6, wm = wave & 1, wn = wave >> 1;
      int chb = (quad ^ (l15 & 7)) << 4;

      f32x4 acc[4][4] = {};
      for (int k0 = 0; k0 < HID; k0 += 64) {
        __syncthreads();
        stage_tile<HID>(hb, row0, k0, As);
        stage_tile<HID>(w2b, col0, k0, Bs);
        __syncthreads();
#pragma unroll
        for (int kk = 0; kk < 2; ++kk) {
          int xo = chb ^ (kk << 6);
          bf16x8 af[4], bg[4];
#pragma unroll
          for (int mt = 0; mt < 4; ++mt)
            af[mt] = *(const bf16x8*)(As + (wm * 64 + mt * 16 + l15) * 128 + xo);
#pragma unroll
          for (int nt = 0; nt < 4; ++nt)
            bg[nt] = *(const bf16x8*)(Bs + (wn * 64 + nt * 16 + l15) * 128 + xo);
#pragma unroll
          for (int mt = 0; mt < 4; ++mt)
#pragma unroll
            for (int nt = 0; nt < 4; ++nt)
              acc[mt][nt] = __builtin_amdgcn_mfma_f32_16x16x32_bf16(
                  af[mt], bg[nt], acc[mt][nt], 0, 0, 0);
        }
      }
      int p_base = row0 + wm * 64;
      int d_base = col0 + wn * 64;
#pragma unroll
      for (int mt = 0; mt < 4; ++mt) {
#pragma unroll
        for (int r = 0; r < 4; ++r) {
          int m2 = rowtok[p_base + mt * 16 + quad * 4 + r];
          int t = m2 & 0x3FFF;
          int dout = 128 << (m2 >> 14);
#pragma unroll
          for (int nt = 0; nt < 4; ++nt) {
            int d = d_base + nt * 16 + l15;
            float v = acc[mt][nt][r] + b2[d];
            out[(size_t)t * DIM + d] = (d < dout) ? v : 0.0f;
          }
        }
      }
    }
  }
}

extern "C" void kernel_launch(void* const* d_in, const int* in_sizes, int n_in,
                              void* d_out, int out_size, void* d_ws, size_t ws_size,
                              hipStream_t stream) {
  const float* x  = (const float*)d_in[0];
  const float* w1 = (const float*)d_in[1];
  const float* b1 = (const float*)d_in[2];
  const float* w2 = (const float*)d_in[3];
  const float* b2 = (const float*)d_in[4];
  const int*   tm = (const int*)d_in[5];
  float* out = (float*)d_out;

  char* ws = (char*)d_ws;
  int* meta = (int*)ws;                                     // 128 KB reserved
  unsigned short* xb  = (unsigned short*)(ws + 131072);     // 32 MB
  unsigned short* w1b = (unsigned short*)(ws + 33685504);   //  8 MB
  unsigned short* w2b = (unsigned short*)(ws + 42074112);   //  8 MB
  unsigned short* hb  = (unsigned short*)(ws + 50462720);   // 128 MB (176.125 MB)

  zero_bar_kernel<<<1, 64, 0, stream>>>(meta);
  mega_kernel<<<NBLK, 256, 0, stream>>>(x, w1, b1, w2, b2, tm, meta,
                                        xb, w1b, w2b, hb, out);
}

// Round 7
// 1218.010 us; speedup vs baseline: 1.3164x; 1.3164x over previous
//
#include <hip/hip_runtime.h>
#include <hip/hip_bf16.h>

// NestedFeedForward, Round 6: persistent mega-kernel v2.
// R5 failed from __launch_bounds__(256,4) register starvation (VGPR capped 64
// -> K-loop fragment spills to scratch -> MfmaUtil 3.3%). v2: (256,3) cap=170
// VGPRs (fits the ~152 the gemm phases need, no spills) and NBLK=768 = 3
// blocks/CU (LDS cap 5/CU, VGPR cap >=3/CU -> all co-resident, barrier safe).
// Phases: hist|w-cvt, meta, scatter, x-cvt, gemm1 (4096 tiles, high-K first),
// gemm2 (2048 64x128 tiles, compute-first map). All R4-measured phase code.

typedef __bf16 bf16x8 __attribute__((ext_vector_type(8)));
typedef float f32x4 __attribute__((ext_vector_type(4)));

#define M_TOK   16384
#define DIM     1024
#define HID     4096
#define NBLK    768

// meta (ints at ws+0):
#define META_T     31
#define META_BAR   32     // 8 barrier slots (zeroed each launch)
#define META_HIST  64     // 64 blocks x 4 experts
#define META_BASE2 384    // 64 x 4 scatter bases
#define META_BLK   640    // 128 kmax per 128-row gemm1 block
#define META_MAP   768    // 2048 gemm2 64x128 tiles, compute-first
#define META_RT    3072   // 16384 rowtok

__device__ inline unsigned short f2bf(float f) {
  unsigned int u = __float_as_uint(f);
  u += 0x7fffu + ((u >> 16) & 1u);      // RNE; inputs finite
  return (unsigned short)(u >> 16);
}

// gelu with A&S 7.1.26 erf: abs err <= ~2.5e-5 (system absmax 0.0039 vs 0.0216)
__device__ inline float gelu_f(float v) {
  float z = fabsf(v) * 0.7071067811865475f;
  float t = __builtin_amdgcn_rcpf(fmaf(0.3275911f, z, 1.0f));
  float p = fmaf(t, 1.061405429f, -1.453152027f);
  p = fmaf(t, p, 1.421413741f);
  p = fmaf(t, p, -0.284496736f);
  p = fmaf(t, p, 0.254829592f);
  p = p * t;
  float E = __expf(-0.5f * v * v);
  float er = fmaf(-p, E, 1.0f);
  er = copysignf(er, v);
  return 0.5f * v * (1.0f + er);
}

__device__ inline void async_copy16(const void* g, void* s) {
  __builtin_amdgcn_global_load_lds(
      (const __attribute__((address_space(1))) unsigned int*)g,
      (__attribute__((address_space(3))) unsigned int*)s,
      16, 0, 0);
}

// Stage a ROWS x 64-col bf16 tile into LDS with XOR chunk swizzle (2-way
// aliasing on b128 readbacks = free, m136).
template<int ROWS, int LDK>
__device__ inline void stage_tile(const unsigned short* __restrict__ g,
                                  int row0, int k0, char* lds) {
  const char* gbase = (const char*)g;
  int tid = threadIdx.x;
#pragma unroll
  for (int i = 0; i < ROWS / 32; ++i) {
    int q = i * 256 + tid;          // ROWS*8 chunks of 16B
    int r = q >> 3;
    int c = q & 7;
    int gc = c ^ (r & 7);
    const void* gp = gbase + ((size_t)(row0 + r) * LDK + (size_t)k0 + gc * 8) * 2;
    async_copy16(gp, lds + (size_t)q * 16);
  }
}

// Grid barrier: every thread fences (drain stores to device-coherent point),
// block syncs, tid0 release-add + acquire-spin, fence (inv L1), block syncs.
// All cross-block data is write-once -> barrier -> read.
__device__ inline void grid_barrier(int* bar) {
  __threadfence();
  __syncthreads();
  if (threadIdx.x == 0) {
    __hip_atomic_fetch_add(bar, 1, __ATOMIC_RELEASE, __HIP_MEMORY_SCOPE_AGENT);
    while (__hip_atomic_load(bar, __ATOMIC_ACQUIRE, __HIP_MEMORY_SCOPE_AGENT) < NBLK)
      __builtin_amdgcn_s_sleep(2);
    __threadfence();
  }
  __syncthreads();
}

__global__ void zero_bar_kernel(int* meta) {
  if (threadIdx.x < 8) meta[META_BAR + threadIdx.x] = 0;
}

__global__ __launch_bounds__(256, 3) void mega_kernel(
    const float* __restrict__ x,  const float* __restrict__ w1,
    const float* __restrict__ b1, const float* __restrict__ w2,
    const float* __restrict__ b2, const int* __restrict__ tm,
    int* __restrict__ meta,
    unsigned short* __restrict__ xb,  unsigned short* __restrict__ w1b,
    unsigned short* __restrict__ w2b, unsigned short* __restrict__ hb,
    float* __restrict__ out)
{
  __shared__ char smem[32768];
  const int blk = blockIdx.x;
  const int tid = threadIdx.x;
  int* bar = meta + META_BAR;

  // ---------- Phase A: histogram (blk<64) | weight convert (blk>=64) ----------
  if (blk < 64) {
    int* h4 = (int*)smem;
    if (tid < 4) h4[tid] = 0;
    __syncthreads();
    atomicAdd(&h4[tm[blk * 256 + tid]], 1);
    __syncthreads();
    if (tid < 4) meta[META_HIST + blk * 4 + tid] = h4[tid];
  } else {
    for (int c = blk - 64; c < 8192; c += NBLK - 64) {   // 8192 x 1024 floats
      const float* src = (c < 4096) ? w1 : w2;
      unsigned short* dst = (c < 4096) ? w1b : w2b;
      size_t i = (size_t)(c & 4095) * 1024 + tid * 4;
      float4 v = *(const float4*)(src + i);
      ushort4 o;
      o.x = f2bf(v.x); o.y = f2bf(v.y); o.z = f2bf(v.z); o.w = f2bf(v.w);
      *(ushort4*)(dst + i) = o;
    }
  }
  grid_barrier(bar + 0);

  // ---------- Phase B: scan + metadata (block 0 only) ----------
  if (blk == 0) {
    int* sb  = (int*)smem;            // [5]
    int* cbl = (int*)smem + 8;        // [256] strip colblock counts
    int* pfx = (int*)smem + 272;      // [257]
    if (tid == 0) {
      int t0 = 0, t1 = 0, t2 = 0, t3 = 0;
      for (int b = 0; b < 64; ++b) {
        t0 += meta[META_HIST + b * 4 + 0];
        t1 += meta[META_HIST + b * 4 + 1];
        t2 += meta[META_HIST + b * 4 + 2];
        t3 += meta[META_HIST + b * 4 + 3];
      }
      sb[0] = 0; sb[1] = t0; sb[2] = t0 + t1; sb[3] = t0 + t1 + t2; sb[4] = M_TOK;
      int r0 = sb[0], r1 = sb[1], r2 = sb[2], r3 = sb[3];
      for (int b = 0; b < 64; ++b) {
        meta[META_BASE2 + b * 4 + 0] = r0; r0 += meta[META_HIST + b * 4 + 0];
        meta[META_BASE2 + b * 4 + 1] = r1; r1 += meta[META_HIST + b * 4 + 1];
        meta[META_BASE2 + b * 4 + 2] = r2; r2 += meta[META_HIST + b * 4 + 2];
        meta[META_BASE2 + b * 4 + 3] = r3; r3 += meta[META_HIST + b * 4 + 3];
      }
    }
    __syncthreads();
    if (tid < 256) {                  // strip = 64 rows
      int last = tid * 64 + 63;
      int e = (last >= sb[1]) + (last >= sb[2]) + (last >= sb[3]);
      cbl[tid] = 1 << e;
      if (tid & 1) meta[META_BLK + (tid >> 1)] = 128 << e;   // gemm1 kmax
    }
    __syncthreads();
    if (tid == 0) {
      int a = 0;
      for (int j = 0; j < 256; ++j) { pfx[j] = a; a += cbl[j]; }
      pfx[256] = a;
      meta[META_T] = a;
    }
    __syncthreads();
    if (tid < 256) {
      int n = cbl[tid], p = pfx[tid];
      for (int c = 0; c < n; ++c) meta[META_MAP + p + c] = tid * 8 + c;
      int zp = pfx[256] + 8 * tid - pfx[tid];
      for (int c = n; c < 8; ++c) meta[META_MAP + zp + (c - n)] = tid * 8 + c;
    }
  }
  grid_barrier(bar + 1);

  // ---------- Phase C: deterministic scatter (blk<64) ----------
  if (blk < 64) {
    int* cnt = (int*)smem;            // [256*5], stride 5 -> conflict-free
    int t = blk * 256 + tid;
    int e = tm[t];
    cnt[tid * 5 + 0] = (e == 0); cnt[tid * 5 + 1] = (e == 1);
    cnt[tid * 5 + 2] = (e == 2); cnt[tid * 5 + 3] = (e == 3);
    __syncthreads();
    for (int s = 1; s < 256; s <<= 1) {
      int v0 = 0, v1 = 0, v2 = 0, v3 = 0;
      if (tid >= s) {
        v0 = cnt[(tid - s) * 5 + 0]; v1 = cnt[(tid - s) * 5 + 1];
        v2 = cnt[(tid - s) * 5 + 2]; v3 = cnt[(tid - s) * 5 + 3];
      }
      __syncthreads();
      cnt[tid * 5 + 0] += v0; cnt[tid * 5 + 1] += v1;
      cnt[tid * 5 + 2] += v2; cnt[tid * 5 + 3] += v3;
      __syncthreads();
    }
    int rank = cnt[tid * 5 + e] - 1;
    int pos = meta[META_BASE2 + blk * 4 + e] + rank;
    meta[META_RT + pos] = t | (e << 14);
  }
  grid_barrier(bar + 2);

  // ---------- Phase D: x gather + bf16 convert ----------
  {
    int d = tid * 4;
    for (int pos = blk; pos < M_TOK; pos += NBLK) {
      int mt = meta[META_RT + pos];
      int t = mt & 0x3FFF;
      int din = 128 << (mt >> 14);
      float4 v = *(const float4*)(x + (size_t)t * DIM + d);
      ushort4 o;
      if (d < din) {                  // din multiple of 128 -> float4-uniform
        o.x = f2bf(v.x); o.y = f2bf(v.y); o.z = f2bf(v.z); o.w = f2bf(v.w);
      } else {
        o.x = 0; o.y = 0; o.z = 0; o.w = 0;
      }
      *(ushort4*)(xb + (size_t)pos * DIM + d) = o;
    }
  }
  grid_barrier(bar + 3);

  // ---------- Phase E: gemm1, grid-stride, high-K tiles first ----------
  {
    char* As = smem;
    char* Bs = smem + 16384;
    int lane = tid & 63, quad = lane >> 4, l15 = lane & 15;
    int wave = tid >> 6, wm = wave & 1, wn = wave >> 1;
    int chb = (quad ^ (l15 & 7)) << 4;

    for (int tile = blk; tile < 4096; tile += NBLK) {
      int rowblk = 127 - (tile >> 5);            // high-K first
      int row0 = rowblk * 128, col0 = (tile & 31) * 128;
      int kmax = meta[META_BLK + rowblk];

      f32x4 acc[4][4] = {};
      for (int k0 = 0; k0 < kmax; k0 += 64) {
        __syncthreads();
        stage_tile<128, DIM>(xb, row0, k0, As);
        stage_tile<128, DIM>(w1b, col0, k0, Bs);
        __syncthreads();
#pragma unroll
        for (int kk = 0; kk < 2; ++kk) {
          int xo = chb ^ (kk << 6);
          bf16x8 af[4], bg[4];
#pragma unroll
          for (int mt = 0; mt < 4; ++mt)
            af[mt] = *(const bf16x8*)(As + (wm * 64 + mt * 16 + l15) * 128 + xo);
#pragma unroll
          for (int nt = 0; nt < 4; ++nt)
            bg[nt] = *(const bf16x8*)(Bs + (wn * 64 + nt * 16 + l15) * 128 + xo);
#pragma unroll
          for (int mt = 0; mt < 4; ++mt)
#pragma unroll
            for (int nt = 0; nt < 4; ++nt)
              acc[mt][nt] = __builtin_amdgcn_mfma_f32_16x16x32_bf16(
                  af[mt], bg[nt], acc[mt][nt], 0, 0, 0);
        }
      }
      int t_base = row0 + wm * 64;
      int f_base = col0 + wn * 64;
#pragma unroll
      for (int nt = 0; nt < 4; ++nt) {
        int f = f_base + nt * 16 + l15;
        float bv = b1[f];
#pragma unroll
        for (int mt = 0; mt < 4; ++mt) {
#pragma unroll
          for (int r = 0; r < 4; ++r) {
            int t = t_base + mt * 16 + quad * 4 + r;
            float v = gelu_f(acc[mt][nt][r] + bv);
            hb[(size_t)t * HID + f] = f2bf(v);
          }
        }
      }
    }
  }
  grid_barrier(bar + 4);

  // ---------- Phase F: gemm2, 64x128 tiles, grid-stride over map ----------
  {
    int T = meta[META_T];
    const int* rowtok = meta + META_RT;
    char* As = smem;                          // 8 KB (64x64)
    char* Bs = smem + 8192;                   // 16 KB (128x64)
    int lane = tid & 63, quad = lane >> 4, l15 = lane & 15;
    int wave = tid >> 6, wm = wave & 1, wn = wave >> 1;
    int chb = (quad ^ (l15 & 7)) << 4;

    for (int tf = blk; tf < 2048; tf += NBLK) {
      int mp = meta[META_MAP + tf];
      int row0 = (mp >> 3) * 64, col0 = (mp & 7) * 128;

      if (tf >= T) {
        float4 z = make_float4(0.f, 0.f, 0.f, 0.f);
#pragma unroll
        for (int i = 0; i < 8; ++i) {
          int idx = i * 256 + tid;            // 2048 float4 = 64x128 tile
          int r = idx >> 5;
          int col = (idx & 31) * 4;
          int t = rowtok[row0 + r] & 0x3FFF;
          *(float4*)(out + (size_t)t * DIM + col0 + col) = z;
        }
        continue;
      }

      f32x4 acc[2][4] = {};
      for (int k0 = 0; k0 < HID; k0 += 64) {
        __syncthreads();
        stage_tile<64, HID>(hb, row0, k0, As);
        stage_tile<128, HID>(w2b, col0, k0, Bs);
        __syncthreads();
#pragma unroll
        for (int kk = 0; kk < 2; ++kk) {
          int xo = chb ^ (kk << 6);
          bf16x8 af[2], bg[4];
#pragma unroll
          for (int mt = 0; mt < 2; ++mt)
            af[mt] = *(const bf16x8*)(As + (wm * 32 + mt * 16 + l15) * 128 + xo);
#pragma unroll
          for (int nt = 0; nt < 4; ++nt)
            bg[nt] = *(const bf16x8*)(Bs + (wn * 64 + nt * 16 + l15) * 128 + xo);
#pragma unroll
          for (int mt = 0; mt < 2; ++mt)
#pragma unroll
            for (int nt = 0; nt < 4; ++nt)
              acc[mt][nt] = __builtin_amdgcn_mfma_f32_16x16x32_bf16(
                  af[mt], bg[nt], acc[mt][nt], 0, 0, 0);
        }
      }
      int p_base = row0 + wm * 32;
      int d_base = col0 + wn * 64;
#pragma unroll
      for (int mt = 0; mt < 2; ++mt) {
#pragma unroll
        for (int r = 0; r < 4; ++r) {
          int m2 = rowtok[p_base + mt * 16 + quad * 4 + r];
          int t = m2 & 0x3FFF;
          int dout = 128 << (m2 >> 14);
#pragma unroll
          for (int nt = 0; nt < 4; ++nt) {
            int d = d_base + nt * 16 + l15;
            float v = acc[mt][nt][r] + b2[d];
            out[(size_t)t * DIM + d] = (d < dout) ? v : 0.0f;
          }
        }
      }
    }
  }
}

extern "C" void kernel_launch(void* const* d_in, const int* in_sizes, int n_in,
                              void* d_out, int out_size, void* d_ws, size_t ws_size,
                              hipStream_t stream) {
  const float* x  = (const float*)d_in[0];
  const float* w1 = (const float*)d_in[1];
  const float* b1 = (const float*)d_in[2];
  const float* w2 = (const float*)d_in[3];
  const float* b2 = (const float*)d_in[4];
  const int*   tm = (const int*)d_in[5];
  float* out = (float*)d_out;

  char* ws = (char*)d_ws;
  int* meta = (int*)ws;                                     // 128 KB reserved
  unsigned short* xb  = (unsigned short*)(ws + 131072);     // 32 MB
  unsigned short* w1b = (unsigned short*)(ws + 33685504);   //  8 MB
  unsigned short* w2b = (unsigned short*)(ws + 42074112);   //  8 MB
  unsigned short* hb  = (unsigned short*)(ws + 50462720);   // 128 MB (176.125 MB)

  zero_bar_kernel<<<1, 64, 0, stream>>>(meta);
  mega_kernel<<<NBLK, 256, 0, stream>>>(x, w1, b1, w2, b2, tm, meta,
                                        xb, w1b, w2b, hb, out);
}

// Round 9
// 368.397 us; speedup vs baseline: 4.3522x; 3.3062x over previous
//
#include <hip/hip_runtime.h>
#include <hip/hip_bf16.h>

// NestedFeedForward, Round 8: R4's fully-proven 4-launch pipeline (sort,
// prep, gemm1, gemm2) with ONE change: output-tail zeroing (out[t, d>=dout])
// moved into prep's cvt_x branch (same d-predicate as the xb zero-padding),
// so gemm2 runs compute tiles only (zero tiles exit instantly, stores
// predicated). R5-R7 experiments (persistent kernel, fused sort, gather
// staging) all regressed or broke and are fully reverted.

typedef __bf16 bf16x8 __attribute__((ext_vector_type(8)));
typedef float f32x4 __attribute__((ext_vector_type(4)));

#define M_TOK   16384
#define DIM     1024
#define HID     4096

// meta (ints at ws+0): [31] T, [64..191] kmax per 128-row gemm1 block,
// [256..2303] gemm2 map (compute tiles first; 2048 = 256 strips x 8 cols),
// [2560..18943] rowtok (t | e<<14).
#define META_T     31
#define META_BLK   64
#define META_MAP   256
#define META_RT    2560

__device__ inline unsigned short f2bf(float f) {
  unsigned int u = __float_as_uint(f);
  u += 0x7fffu + ((u >> 16) & 1u);      // RNE; inputs finite
  return (unsigned short)(u >> 16);
}

// gelu with A&S 7.1.26 erf: abs err <= ~2.5e-5 (system absmax 0.0039 vs 0.0216)
__device__ inline float gelu_f(float v) {
  float z = fabsf(v) * 0.7071067811865475f;
  float t = __builtin_amdgcn_rcpf(fmaf(0.3275911f, z, 1.0f));
  float p = fmaf(t, 1.061405429f, -1.453152027f);
  p = fmaf(t, p, 1.421413741f);
  p = fmaf(t, p, -0.284496736f);
  p = fmaf(t, p, 0.254829592f);
  p = p * t;
  float E = __expf(-0.5f * v * v);
  float er = fmaf(-p, E, 1.0f);
  er = copysignf(er, v);
  return 0.5f * v * (1.0f + er);
}

__device__ inline void async_copy16(const void* g, void* s) {
  __builtin_amdgcn_global_load_lds(
      (const __attribute__((address_space(1))) unsigned int*)g,
      (__attribute__((address_space(3))) unsigned int*)s,
      16, 0, 0);
}

// Stage a ROWS x 64-col bf16 tile into LDS with XOR chunk swizzle (2-way
// aliasing on the b128 readbacks = free, m136).
template<int ROWS, int LDK>
__device__ inline void stage_tile(const unsigned short* __restrict__ g,
                                  int row0, int k0, char* lds) {
  const char* gbase = (const char*)g;
  int tid = threadIdx.x;
#pragma unroll
  for (int i = 0; i < ROWS / 32; ++i) {
    int q = i * 256 + tid;          // ROWS*8 chunks of 16B
    int r = q >> 3;
    int c = q & 7;
    int gc = c ^ (r & 7);
    const void* gp = gbase + ((size_t)(row0 + r) * LDK + (size_t)k0 + gc * 8) * 2;
    async_copy16(gp, lds + (size_t)q * 16);
  }
}

// ---------------- fused sort + metadata (single block) — R4-proven ----------
__global__ __launch_bounds__(1024) void sort_kernel(const int* __restrict__ tm,
                                                    int* __restrict__ meta) {
  __shared__ int cnt[1024][5];      // stride 5 dwords -> conflict-free
  __shared__ int sbase[5];
  __shared__ int cb[256];
  __shared__ int pfx[257];
  int tid = threadIdx.x;

  int c0 = 0, c1 = 0, c2 = 0, c3 = 0;
  unsigned int epack = 0;
  int4 tv[4];
#pragma unroll
  for (int j = 0; j < 4; ++j)
    tv[j] = *(const int4*)(tm + tid * 16 + j * 4);
#pragma unroll
  for (int j = 0; j < 4; ++j) {
    int e;
    e = tv[j].x; epack |= (unsigned)e << (2 * (4 * j + 0)); c0 += (e == 0); c1 += (e == 1); c2 += (e == 2); c3 += (e == 3);
    e = tv[j].y; epack |= (unsigned)e << (2 * (4 * j + 1)); c0 += (e == 0); c1 += (e == 1); c2 += (e == 2); c3 += (e == 3);
    e = tv[j].z; epack |= (unsigned)e << (2 * (4 * j + 2)); c0 += (e == 0); c1 += (e == 1); c2 += (e == 2); c3 += (e == 3);
    e = tv[j].w; epack |= (unsigned)e << (2 * (4 * j + 3)); c0 += (e == 0); c1 += (e == 1); c2 += (e == 2); c3 += (e == 3);
  }
  cnt[tid][0] = c0; cnt[tid][1] = c1; cnt[tid][2] = c2; cnt[tid][3] = c3;
  __syncthreads();
  for (int s = 1; s < 1024; s <<= 1) {
    int v0 = 0, v1 = 0, v2 = 0, v3 = 0;
    if (tid >= s) {
      v0 = cnt[tid - s][0]; v1 = cnt[tid - s][1];
      v2 = cnt[tid - s][2]; v3 = cnt[tid - s][3];
    }
    __syncthreads();
    cnt[tid][0] += v0; cnt[tid][1] += v1; cnt[tid][2] += v2; cnt[tid][3] += v3;
    __syncthreads();
  }
  if (tid == 0) {
    int b = 0;
#pragma unroll
    for (int e = 0; e < 4; ++e) { sbase[e] = b; b += cnt[1023][e]; }
    sbase[4] = b;
  }
  __syncthreads();
  int off0 = sbase[0] + cnt[tid][0] - c0;
  int off1 = sbase[1] + cnt[tid][1] - c1;
  int off2 = sbase[2] + cnt[tid][2] - c2;
  int off3 = sbase[3] + cnt[tid][3] - c3;
  int* rowtok = meta + META_RT;
#pragma unroll
  for (int j = 0; j < 16; ++j) {
    int e = (epack >> (2 * j)) & 3;
    int t = tid * 16 + j;
    int pos = (e == 0) ? off0++ : (e == 1) ? off1++ : (e == 2) ? off2++ : off3++;
    rowtok[pos] = t | (e << 14);
  }
  // strip-level (64-row) metadata for gemm2 + 128-row kmax for gemm1
  if (tid < 256) {
    int last = tid * 64 + 63;
    int e = (last >= sbase[1]) + (last >= sbase[2]) + (last >= sbase[3]);
    cb[tid] = 1 << e;                       // compute colblocks for this strip
    if (tid & 1) meta[META_BLK + (tid >> 1)] = 128 << e;   // 128-block kmax
  }
  __syncthreads();
  if (tid == 0) {
    int acc = 0;
    for (int j = 0; j < 256; ++j) { pfx[j] = acc; acc += cb[j]; }
    pfx[256] = acc;
    meta[META_T] = acc;
  }
  __syncthreads();
  if (tid < 256) {
    int n = cb[tid];
    int p = pfx[tid];
    int* map = meta + META_MAP;
    for (int c = 0; c < n; ++c) map[p + c] = tid * 8 + c;
    int zp = pfx[256] + 8 * tid - pfx[tid];          // zeros before this strip
    for (int c = n; c < 8; ++c) map[zp + (c - n)] = tid * 8 + c;
  }
}

// ------- fused prep: cvt_x (permuted gather) + out-tail zero + w1/w2 -------
__global__ void prep_kernel(const float* __restrict__ x,
                            const float* __restrict__ w1,
                            const float* __restrict__ w2,
                            const int* __restrict__ meta,
                            unsigned short* __restrict__ xb,
                            unsigned short* __restrict__ w1b,
                            unsigned short* __restrict__ w2b,
                            float* __restrict__ out) {
  int b = blockIdx.x;
  int tid = threadIdx.x;
  if (b < M_TOK) {
    int mt = meta[META_RT + b];
    int t = mt & 0x3FFF;
    int din = 128 << (mt >> 14);    // == dout for this token
    int d = tid * 4;
    float4 v = *(const float4*)(x + (size_t)t * DIM + d);
    ushort4 o;
    if (d < din) {                  // din multiple of 128 -> float4-uniform
      o.x = f2bf(v.x); o.y = f2bf(v.y); o.z = f2bf(v.z); o.w = f2bf(v.w);
    } else {
      o.x = 0; o.y = 0; o.z = 0; o.w = 0;
      // pre-zero the masked output region (out is poisoned each launch);
      // gemm2 then never writes zeros.
      *(float4*)(out + (size_t)t * DIM + d) = make_float4(0.f, 0.f, 0.f, 0.f);
    }
    *(ushort4*)(xb + (size_t)b * DIM + d) = o;
  } else {
    size_t i = (size_t)(b - M_TOK) * 1024 + tid * 4;   // 0 .. 8388607
    const float* src;
    unsigned short* dst;
    if (i < (size_t)HID * DIM) { src = w1; dst = w1b; }
    else { src = w2 - (size_t)HID * DIM; dst = w2b - (size_t)HID * DIM; }
    float4 v = *(const float4*)(src + i);
    ushort4 o;
    o.x = f2bf(v.x); o.y = f2bf(v.y); o.z = f2bf(v.z); o.w = f2bf(v.w);
    *(ushort4*)(dst + i) = o;
  }
}

// ---- GEMM1: hb[pos,f] = gelu( xb[pos,:] . w1b[f,:] + b1[f] ), bf16 out ----
// R4-proven: high-K rowblocks first, colblock fast-varying, K trimmed to kmax.
__global__ __launch_bounds__(256) void gemm1_kernel(
    const unsigned short* __restrict__ A,   // xb [16384,1024] bf16 (permuted)
    const unsigned short* __restrict__ B,   // w1b [4096,1024] bf16
    const float* __restrict__ bias,         // b1 [4096]
    const int* __restrict__ meta,
    unsigned short* __restrict__ H)         // hb [16384,4096] bf16 (permuted)
{
  constexpr int K = DIM, N = HID;
  __shared__ char smem[32768];
  char* As = smem;
  char* Bs = smem + 16384;
  int tid = threadIdx.x;
  int lane = tid & 63, quad = lane >> 4, l15 = lane & 15;
  int wave = tid >> 6, wm = wave & 1, wn = wave >> 1;
  int rowblk = 127 - (blockIdx.x >> 5);
  int row0 = rowblk * 128, col0 = (blockIdx.x & 31) * 128;
  int kmax = meta[META_BLK + rowblk];

  int chb = (quad ^ (l15 & 7)) << 4;        // staging swizzle base

  f32x4 acc[4][4] = {};

  for (int k0 = 0; k0 < kmax; k0 += 64) {
    __syncthreads();
    stage_tile<128, K>(A, row0, k0, As);
    stage_tile<128, K>(B, col0, k0, Bs);
    __syncthreads();
#pragma unroll
    for (int kk = 0; kk < 2; ++kk) {
      int xo = chb ^ (kk << 6);
      bf16x8 af[4], bg[4];
#pragma unroll
      for (int mt = 0; mt < 4; ++mt)
        af[mt] = *(const bf16x8*)(As + (wm * 64 + mt * 16 + l15) * 128 + xo);
#pragma unroll
      for (int nt = 0; nt < 4; ++nt)
        bg[nt] = *(const bf16x8*)(Bs + (wn * 64 + nt * 16 + l15) * 128 + xo);
#pragma unroll
      for (int mt = 0; mt < 4; ++mt)
#pragma unroll
        for (int nt = 0; nt < 4; ++nt)
          acc[mt][nt] = __builtin_amdgcn_mfma_f32_16x16x32_bf16(
              af[mt], bg[nt], acc[mt][nt], 0, 0, 0);
    }
  }

  // Direct-store epilogue (measured faster than LDS round-trip: R2 vs R3)
  int t_base = row0 + wm * 64;
  int f_base = col0 + wn * 64;
#pragma unroll
  for (int nt = 0; nt < 4; ++nt) {
    int f = f_base + nt * 16 + l15;
    float bv = bias[f];
#pragma unroll
    for (int mt = 0; mt < 4; ++mt) {
#pragma unroll
      for (int r = 0; r < 4; ++r) {
        int t = t_base + mt * 16 + quad * 4 + r;
        float v = gelu_f(acc[mt][nt][r] + bv);
        H[(size_t)t * N + f] = f2bf(v);
      }
    }
  }
}

// ---- GEMM2: 64x128 compute tiles only; tf>=T exits (zeros pre-filled) ----
__global__ __launch_bounds__(256) void gemm2_kernel(
    const unsigned short* __restrict__ A,   // hb [16384,4096] bf16 (permuted)
    const unsigned short* __restrict__ B,   // w2b [1024,4096] bf16
    const float* __restrict__ bias,         // b2 [1024]
    const int* __restrict__ meta,
    float* __restrict__ out)                // [16384,1024] fp32
{
  constexpr int K = HID, N = DIM;
  int T = meta[META_T];
  int tf = blockIdx.x;
  if (tf >= T) return;                      // masked region zeroed by prep
  int mp = meta[META_MAP + tf];
  int row0 = (mp >> 3) * 64, col0 = (mp & 7) * 128;
  const int* rowtok = meta + META_RT;
  int tid = threadIdx.x;

  __shared__ char smem[24576];
  char* As = smem;                          // 8 KB (64x64)
  char* Bs = smem + 8192;                   // 16 KB (128x64)
  int lane = tid & 63, quad = lane >> 4, l15 = lane & 15;
  int wave = tid >> 6, wm = wave & 1, wn = wave >> 1;
  int chb = (quad ^ (l15 & 7)) << 4;

  f32x4 acc[2][4] = {};

  for (int k0 = 0; k0 < K; k0 += 64) {
    __syncthreads();
    stage_tile<64, K>(A, row0, k0, As);
    stage_tile<128, K>(B, col0, k0, Bs);
    __syncthreads();
#pragma unroll
    for (int kk = 0; kk < 2; ++kk) {
      int xo = chb ^ (kk << 6);
      bf16x8 af[2], bg[4];
#pragma unroll
      for (int mt = 0; mt < 2; ++mt)
        af[mt] = *(const bf16x8*)(As + (wm * 32 + mt * 16 + l15) * 128 + xo);
#pragma unroll
      for (int nt = 0; nt < 4; ++nt)
        bg[nt] = *(const bf16x8*)(Bs + (wn * 64 + nt * 16 + l15) * 128 + xo);
#pragma unroll
      for (int mt = 0; mt < 2; ++mt)
#pragma unroll
        for (int nt = 0; nt < 4; ++nt)
          acc[mt][nt] = __builtin_amdgcn_mfma_f32_16x16x32_bf16(
              af[mt], bg[nt], acc[mt][nt], 0, 0, 0);
    }
  }

  int p_base = row0 + wm * 32;
  int d_base = col0 + wn * 64;
#pragma unroll
  for (int mt = 0; mt < 2; ++mt) {
#pragma unroll
    for (int r = 0; r < 4; ++r) {
      int m2 = rowtok[p_base + mt * 16 + quad * 4 + r];
      int t = m2 & 0x3FFF;
      int dout = 128 << (m2 >> 14);
#pragma unroll
      for (int nt = 0; nt < 4; ++nt) {
        int d = d_base + nt * 16 + l15;
        if (d < dout)                        // zeros already written by prep
          out[(size_t)t * N + d] = acc[mt][nt][r] + bias[d];
      }
    }
  }
}

extern "C" void kernel_launch(void* const* d_in, const int* in_sizes, int n_in,
                              void* d_out, int out_size, void* d_ws, size_t ws_size,
                              hipStream_t stream) {
  const float* x  = (const float*)d_in[0];
  const float* w1 = (const float*)d_in[1];
  const float* b1 = (const float*)d_in[2];
  const float* w2 = (const float*)d_in[3];
  const float* b2 = (const float*)d_in[4];
  const int*   tm = (const int*)d_in[5];
  float* out = (float*)d_out;

  char* ws = (char*)d_ws;
  int* meta = (int*)ws;                                     // 128 KB reserved
  unsigned short* xb  = (unsigned short*)(ws + 131072);     // 32 MB
  unsigned short* w1b = (unsigned short*)(ws + 33685504);   //  8 MB
  unsigned short* w2b = (unsigned short*)(ws + 42074112);   //  8 MB
  unsigned short* hb  = (unsigned short*)(ws + 50462720);   // 128 MB (176.125 MB)

  sort_kernel<<<1, 1024, 0, stream>>>(tm, meta);
  prep_kernel<<<M_TOK + 8192, 256, 0, stream>>>(x, w1, w2, meta, xb, w1b, w2b, out);
  gemm1_kernel<<<4096, 256, 0, stream>>>(xb, w1b, b1, meta, hb);
  gemm2_kernel<<<2048, 256, 0, stream>>>(hb, w2b, b2, meta, out);
}